// Round 1
// 1198.338 us; speedup vs baseline: 1.0804x; 1.0804x over previous
//
#include <hip/hip_runtime.h>

typedef unsigned short UST;
typedef __bf16 bf16x8 __attribute__((ext_vector_type(8)));
typedef float f32x4 __attribute__((ext_vector_type(4)));
typedef float f32x8 __attribute__((ext_vector_type(8)));

__device__ __forceinline__ UST f2bf(float f) {
  return __builtin_bit_cast(UST, (__bf16)f);
}

// split 8 fp32 -> bf16 hi + bf16 lo (residual), packed 16B each
__device__ __forceinline__ void split8v(f32x8 f, uint4& h, uint4& l) {
  UST hh[8], ll[8];
#pragma unroll
  for (int i = 0; i < 8; ++i) {
    float v = f[i];
    __bf16 hb = (__bf16)v;
    hh[i] = __builtin_bit_cast(UST, hb);
    ll[i] = __builtin_bit_cast(UST, (__bf16)(v - (float)hb));
  }
  h = *(uint4*)hh; l = *(uint4*)ll;
}

// chunk-local row p = bn_local*64 + t  ->  absolute token row b*12544 + t*196 + n
__device__ __forceinline__ size_t tok_row(int p, int bn0) {
  const int bn = bn0 + (p >> 6);
  const int b  = bn / 196;
  const int n  = bn - b * 196;
  return (size_t)b * 12544 + (size_t)(p & 63) * 196 + (size_t)n;
}

// async global->LDS, 16B per lane; LDS dest is wave-uniform base + lane*16
__device__ __forceinline__ void gl_lds16(const void* g, void* l) {
  __builtin_amdgcn_global_load_lds(
      (__attribute__((address_space(1))) void*)g,
      (__attribute__((address_space(3))) void*)l, 16, 0, 0);
}

// one-time fp32 -> split bf16 (hi/lo), 8 elems/thread, grid-stride
__global__ __launch_bounds__(256) void split_f32(
    const float* __restrict__ in, UST* __restrict__ hi, UST* __restrict__ lo,
    int n8)
{
  for (int i = blockIdx.x * 256 + threadIdx.x; i < n8; i += gridDim.x * 256) {
    f32x8 v = *(const f32x8*)(in + (size_t)i * 8);
    uint4 h, l;
    split8v(v, h, l);
    *(uint4*)(hi + (size_t)i * 8) = h;
    *(uint4*)(lo + (size_t)i * 8) = l;
  }
}

// C = A @ Bt^T (+bias); A,Bt pre-split bf16 hi/lo (row-major, K contiguous).
// Internally 3-MFMA split product (AhBh + AhBl + AlBh) == old split8v path.
// M%128==0, N%128==0, K%32==0.
// pmode: 1 -> A-rows via tok_row, 2 -> C-rows via tok_row.
// Output: Cb (bf16) if non-null, else Cf (fp32).
__global__ __launch_bounds__(256) void gemm_pre(
    const UST* __restrict__ Agh, const UST* __restrict__ Agl,
    const UST* __restrict__ Bgh, const UST* __restrict__ Bgl,
    const float* __restrict__ bias, float* __restrict__ Cf,
    UST* __restrict__ Cb,
    int M, int N, int K, int pmode, int bn0)
{
  __shared__ __align__(16) UST Ah[128 * 32];
  __shared__ __align__(16) UST Al[128 * 32];
  __shared__ __align__(16) UST Bh[128 * 32];
  __shared__ __align__(16) UST Bl[128 * 32];

  const int tid  = threadIdx.x;
  const int lane = tid & 63;
  const int wv   = tid >> 6;
  const int wr   = wv >> 1;
  const int wc   = wv & 1;
  const int lm   = lane & 15;
  const int lq   = lane >> 4;

  const int m0 = blockIdx.y * 128;
  const int n0 = blockIdx.x * 128;

  f32x4 acc[4][4] = {};

  // staging: thread covers (row sr, cols sc..sc+7) in round 0, row sr+64 in round 1
  const int sr = tid >> 2;               // 0..63
  const int sc = (tid & 3) * 8;          // 0,8,16,24

  const int ar1 = m0 + sr, ar2 = ar1 + 64;
  const size_t ga1 = (pmode == 1) ? tok_row(ar1, bn0) : (size_t)ar1;
  const size_t ga2 = (pmode == 1) ? tok_row(ar2, bn0) : (size_t)ar2;
  const UST* pA1h = Agh + ga1 * K + sc;
  const UST* pA2h = Agh + ga2 * K + sc;
  const UST* pA1l = Agl + ga1 * K + sc;
  const UST* pA2l = Agl + ga2 * K + sc;
  const UST* pB1h = Bgh + (size_t)(n0 + sr) * K + sc;
  const UST* pB2h = Bgh + (size_t)(n0 + sr + 64) * K + sc;
  const UST* pB1l = Bgl + (size_t)(n0 + sr) * K + sc;
  const UST* pB2l = Bgl + (size_t)(n0 + sr + 64) * K + sc;

  // wave-uniform LDS bases: round r, wave w covers 16B-chunks [r*256+w*64, +64)
  const int l0 = wv * 64 * 8;            // UST index of chunk (0*256 + wv*64)
  const int l1 = (256 + wv * 64) * 8;    // UST index of chunk (1*256 + wv*64)

  for (int k0 = 0; k0 < K; k0 += 32) {
    __syncthreads();                     // prior iter's frag reads done
    gl_lds16(pA1h + k0, &Ah[l0]);
    gl_lds16(pA2h + k0, &Ah[l1]);
    gl_lds16(pA1l + k0, &Al[l0]);
    gl_lds16(pA2l + k0, &Al[l1]);
    gl_lds16(pB1h + k0, &Bh[l0]);
    gl_lds16(pB2h + k0, &Bh[l1]);
    gl_lds16(pB1l + k0, &Bl[l0]);
    gl_lds16(pB2l + k0, &Bl[l1]);
    __syncthreads();                     // vmcnt(0) drain: staged tile visible

    bf16x8 afh[4], afl[4], bfh[4], bfl[4];
#pragma unroll
    for (int i = 0; i < 4; ++i) {
      const int off = (wr * 64 + i * 16 + lm) * 32 + lq * 8;
      afh[i] = *(const bf16x8*)(Ah + off);
      afl[i] = *(const bf16x8*)(Al + off);
    }
#pragma unroll
    for (int j = 0; j < 4; ++j) {
      const int off = (wc * 64 + j * 16 + lm) * 32 + lq * 8;
      bfh[j] = *(const bf16x8*)(Bh + off);
      bfl[j] = *(const bf16x8*)(Bl + off);
    }
#pragma unroll
    for (int i = 0; i < 4; ++i)
#pragma unroll
      for (int j = 0; j < 4; ++j) {
        acc[i][j] = __builtin_amdgcn_mfma_f32_16x16x32_bf16(afh[i], bfh[j], acc[i][j], 0, 0, 0);
        acc[i][j] = __builtin_amdgcn_mfma_f32_16x16x32_bf16(afh[i], bfl[j], acc[i][j], 0, 0, 0);
        acc[i][j] = __builtin_amdgcn_mfma_f32_16x16x32_bf16(afl[i], bfh[j], acc[i][j], 0, 0, 0);
      }
  }

  // epilogue: C/D layout col=lane&15, row=quad*4+reg
#pragma unroll
  for (int j = 0; j < 4; ++j) {
    const int n = n0 + wc * 64 + j * 16 + lm;
    const float bv = bias ? bias[n] : 0.0f;
#pragma unroll
    for (int i = 0; i < 4; ++i) {
      const int pb = m0 + wr * 64 + i * 16 + lq * 4;
#pragma unroll
      for (int r = 0; r < 4; ++r) {
        const int p = pb + r;
        const size_t g = (pmode == 2) ? tok_row(p, bn0) : (size_t)p;
        const float v = acc[i][j][r] + bv;
        if (Cb) Cb[g * (size_t)N + n] = f2bf(v);
        else    Cf[g * (size_t)N + n] = v;
      }
    }
  }
}

// One block per (chunk-local bn, head): causal attention, T=64, hd=64.
// qkv: chunk-local (64*NBc, 2304) bf16.  out: split bf16 hi/lo (64*NBc, 768).
#define SQ_STRIDE 67
#define TS 72

__global__ __launch_bounds__(256) void attn64(
    const UST* __restrict__ qkv, UST* __restrict__ oh, UST* __restrict__ ol)
{
  const int nl = blockIdx.x;
  const int h  = blockIdx.y;

  __shared__ __align__(16) UST Qs[64 * TS];
  __shared__ __align__(16) UST Ks[64 * TS];
  __shared__ __align__(16) UST Vt[64 * TS];   // V^T, XOR-swizzled k-blocks
  __shared__ __align__(16) UST Ps[64 * TS];   // exp(S-M) bf16
  __shared__ float Ss[64 * SQ_STRIDE];
  __shared__ float red[4 * 64];
  __shared__ float denom[64];

  const int tid  = threadIdx.x;
  const int lane = tid & 63;
  const int wv   = tid >> 6;
  const int lm   = lane & 15;
  const int lq   = lane >> 4;

  // ---- stage Q, K (bf16) and V^T (XOR-swizzled) ----
#pragma unroll
  for (int it = 0; it < 2; ++it) {
    const int idx = it * 256 + tid;      // ushort8-chunk id, 0..511
    const int t   = idx >> 3;            // row 0..63
    const int f0  = (idx & 7) * 8;       // col 0..56
    const UST* row = qkv + (size_t)(nl * 64 + t) * 2304 + h * 64 + f0;
    uint4 qv = *(const uint4*)row;
    uint4 kv = *(const uint4*)(row + 768);
    uint4 vv = *(const uint4*)(row + 1536);
    *(uint4*)(&Qs[t * TS + f0]) = qv;
    *(uint4*)(&Ks[t * TS + f0]) = kv;
    UST vs[8];
    *(uint4*)vs = vv;
    const int cb = t >> 3;
#pragma unroll
    for (int i = 0; i < 8; ++i) {
      const int d = f0 + i;
      // element V[t][d] stored at Vt[d][ ((cb ^ (d>>3))&7)*8 + (t&7) ]
      Vt[d * TS + (((cb ^ (d >> 3)) & 7) << 3) + (t & 7)] = vs[i];
    }
  }
  __syncthreads();

  // ---- S = Q K^T : wave wv computes rows [wv*16, wv*16+16) x all 64 cols ----
  f32x4 accS[4] = {};
#pragma unroll
  for (int s = 0; s < 2; ++s) {
    bf16x8 aq = *(const bf16x8*)(&Qs[(wv * 16 + lm) * TS + s * 32 + lq * 8]);
#pragma unroll
    for (int j = 0; j < 4; ++j) {
      bf16x8 bk = *(const bf16x8*)(&Ks[(j * 16 + lm) * TS + s * 32 + lq * 8]);
      accS[j] = __builtin_amdgcn_mfma_f32_16x16x32_bf16(aq, bk, accS[j], 0, 0, 0);
    }
  }

  // write masked, scaled scores (C/D layout: col=lane&15, row=quad*4+reg)
#pragma unroll
  for (int j = 0; j < 4; ++j)
#pragma unroll
    for (int r = 0; r < 4; ++r) {
      const int q = wv * 16 + lq * 4 + r;
      const int c = j * 16 + lm;
      Ss[q * SQ_STRIDE + c] = (c > q) ? -1e30f : accS[j][r] * 0.125f;
    }
  __syncthreads();

  // ---- softmax: thread handles row r=tid>>2, cols [seg*16, seg*16+16) ----
  {
    const int r = tid >> 2;
    const int seg = tid & 3;
    const float* srow = &Ss[r * SQ_STRIDE + seg * 16];
    float mx = -1e30f;
#pragma unroll
    for (int c = 0; c < 16; ++c) mx = fmaxf(mx, srow[c]);
    red[seg * 64 + r] = mx;
  }
  __syncthreads();
  {
    const int r = tid >> 2;
    const int seg = tid & 3;
    const float M = fmaxf(fmaxf(red[r], red[64 + r]), fmaxf(red[128 + r], red[192 + r]));
    float ssum = 0.f;
#pragma unroll
    for (int c = 0; c < 16; ++c) {
      const int col = seg * 16 + c;
      float e = 0.f;
      if (col <= r) e = __expf(Ss[r * SQ_STRIDE + col] - M);
      Ps[r * TS + col] = f2bf(e);
      ssum += e;
    }
    __syncthreads();           // all reads of red done before overwrite
    red[seg * 64 + r] = ssum;
  }
  __syncthreads();
  if (tid < 64)
    denom[tid] = red[tid] + red[64 + tid] + red[128 + tid] + red[192 + tid];
  __syncthreads();

  // ---- O = P V : wave wv computes rows [wv*16,+16) x d=0..63 ----
  f32x4 accO[4] = {};
#pragma unroll
  for (int s = 0; s < 2; ++s) {
    bf16x8 ap = *(const bf16x8*)(&Ps[(wv * 16 + lm) * TS + s * 32 + lq * 8]);
#pragma unroll
    for (int j = 0; j < 4; ++j) {
      const int d = j * 16 + lm;
      const int cb = s * 4 + lq;
      bf16x8 bv = *(const bf16x8*)(&Vt[d * TS + (((cb ^ (d >> 3)) & 7) << 3)]);
      accO[j] = __builtin_amdgcn_mfma_f32_16x16x32_bf16(ap, bv, accO[j], 0, 0, 0);
    }
  }

  float inv[4];
#pragma unroll
  for (int r = 0; r < 4; ++r) inv[r] = 1.0f / denom[wv * 16 + lq * 4 + r];
#pragma unroll
  for (int j = 0; j < 4; ++j)
#pragma unroll
    for (int r = 0; r < 4; ++r) {
      const int q = wv * 16 + lq * 4 + r;
      const int d = j * 16 + lm;
      const float o = accO[j][r] * inv[r];
      const __bf16 hb = (__bf16)o;
      const size_t gi = (size_t)(nl * 64 + q) * 768 + h * 64 + d;
      oh[gi] = __builtin_bit_cast(UST, hb);
      ol[gi] = f2bf(o - (float)hb);
    }
}

// Diagnostic fallback: ws too small -> fill output with 1.0f.
__global__ void fill_one(float* p, int n) {
  for (int i = blockIdx.x * 256 + threadIdx.x; i < n; i += gridDim.x * 256)
    p[i] = 1.0f;
}

extern "C" void kernel_launch(void* const* d_in, const int* in_sizes, int n_in,
                              void* d_out, int out_size, void* d_ws, size_t ws_size,
                              hipStream_t stream)
{
  const float* x      = (const float*)d_in[0];
  const float* w_qkv  = (const float*)d_in[1];
  const float* w_proj = (const float*)d_in[2];
  const float* b_proj = (const float*)d_in[3];
  float* out = (float*)d_out;

  const size_t XN = 38535168ull;          // 4*64*196*768
  const size_t WQ = 2304ull * 768;        // 1769472
  const size_t WP = 768ull * 768;         // 589824
  const size_t fixed_b = 2 * (2 * XN + 2 * WQ + 2 * WP);  // bytes: Xh/Xl,Wh/Wl,Ph/Pl
  // per-bn bytes: qkv 64*2304*2 + Oh/Ol 2*64*768*2
  const size_t per_bn = 64ull * 2304 * 2 + 2ull * 64 * 768 * 2;   // 491520

  static const int cands[] = {784, 392, 196, 112, 56, 28, 14, 8, 4, 2};
  int NBc = 0;
  for (int i = 0; i < 10; ++i) {
    if (fixed_b + (size_t)cands[i] * per_bn <= ws_size) { NBc = cands[i]; break; }
  }

  if (NBc == 0) {
    fill_one<<<512, 256, 0, stream>>>(out, out_size);
    return;
  }

  UST* Xh  = (UST*)d_ws;
  UST* Xl  = Xh + XN;
  UST* Wh  = Xl + XN;
  UST* Wl  = Wh + WQ;
  UST* Ph  = Wl + WQ;
  UST* Pl  = Ph + WP;
  UST* qkv = Pl + WP;                       // NBc*64*2304 bf16
  UST* Oh  = qkv + (size_t)NBc * 64 * 2304;
  UST* Ol  = Oh + (size_t)NBc * 64 * 768;

  // one-time splits (per launch)
  split_f32<<<2048, 256, 0, stream>>>(x, Xh, Xl, (int)(XN / 8));
  split_f32<<<864, 256, 0, stream>>>(w_qkv, Wh, Wl, (int)(WQ / 8));
  split_f32<<<288, 256, 0, stream>>>(w_proj, Ph, Pl, (int)(WP / 8));

  const int Mi = NBc * 64;
  for (int bn0 = 0; bn0 < 784; bn0 += NBc) {
    dim3 g1(2304 / 128, Mi / 128);
    gemm_pre<<<g1, 256, 0, stream>>>(Xh, Xl, Wh, Wl, nullptr, nullptr, qkv,
                                     Mi, 2304, 768, /*pmode=*/1, bn0);
    dim3 ga(NBc, 12);
    attn64<<<ga, 256, 0, stream>>>(qkv, Oh, Ol);
    dim3 g2(768 / 128, Mi / 128);
    gemm_pre<<<g2, 256, 0, stream>>>(Oh, Ol, Ph, Pl, b_proj, out, nullptr,
                                     Mi, 768, 768, /*pmode=*/2, bn0);
  }
}

// Round 3
// 1030.883 us; speedup vs baseline: 1.2558x; 1.1624x over previous
//
#include <hip/hip_runtime.h>

typedef unsigned short UST;
typedef __bf16 bf16x8 __attribute__((ext_vector_type(8)));
typedef float f32x4 __attribute__((ext_vector_type(4)));
typedef float f32x8 __attribute__((ext_vector_type(8)));

__device__ __forceinline__ UST f2bf(float f) {
  return __builtin_bit_cast(UST, (__bf16)f);
}

// split 8 fp32 -> bf16 hi + bf16 lo (residual), packed 16B each
__device__ __forceinline__ void split8v(f32x8 f, uint4& h, uint4& l) {
  UST hh[8], ll[8];
#pragma unroll
  for (int i = 0; i < 8; ++i) {
    float v = f[i];
    __bf16 hb = (__bf16)v;
    hh[i] = __builtin_bit_cast(UST, hb);
    ll[i] = __builtin_bit_cast(UST, (__bf16)(v - (float)hb));
  }
  h = *(uint4*)hh; l = *(uint4*)ll;
}

// chunk-local row p = bn_local*64 + t  ->  absolute token row b*12544 + t*196 + n
__device__ __forceinline__ size_t tok_row(int p, int bn0) {
  const int bn = bn0 + (p >> 6);
  const int b  = bn / 196;
  const int n  = bn - b * 196;
  return (size_t)b * 12544 + (size_t)(p & 63) * 196 + (size_t)n;
}

// async global->LDS, 16B per lane; LDS dest is wave-uniform base + lane*16
__device__ __forceinline__ void gl_lds16(const UST* g, UST* l) {
  __builtin_amdgcn_global_load_lds(
      (const __attribute__((address_space(1))) void*)g,
      (__attribute__((address_space(3))) void*)l, 16, 0, 0);
}

// one-time fp32 -> split bf16 (hi/lo), 8 elems/thread, grid-stride
__global__ __launch_bounds__(256) void split_f32(
    const float* __restrict__ in, UST* __restrict__ hi, UST* __restrict__ lo,
    int n8)
{
  for (int i = blockIdx.x * 256 + threadIdx.x; i < n8; i += gridDim.x * 256) {
    f32x8 v = *(const f32x8*)(in + (size_t)i * 8);
    uint4 h, l;
    split8v(v, h, l);
    *(uint4*)(hi + (size_t)i * 8) = h;
    *(uint4*)(lo + (size_t)i * 8) = l;
  }
}

#define SBAR()   __builtin_amdgcn_s_barrier()
#define SCHED0() __builtin_amdgcn_sched_barrier(0)
#define WAIT_VM0() do { asm volatile("s_waitcnt vmcnt(0)" ::: "memory"); SCHED0(); } while (0)

// ---- 256x256x(BK=32) 8-wave split-bf16 GEMM, minimum-2-phase dbuf schedule ----
// C = A @ Bt^T (+bias); A,Bt pre-split bf16 hi/lo, K contiguous. M%256==0, N%256==0, K%32==0.
// pmode: 1 -> A-rows via tok_row, 2 -> C-rows via tok_row.
// Output: Cb (bf16) if non-null, else Cf (fp32).
// LDS swizzle (st_16x32 analog, both-sides): within each 16-row x 64B subtile,
// 16B-chunk bit1 ^= row bit3. Dest stays linear for global_load_lds; the
// permutation lives in the per-lane GLOBAL source chunk and the ds_read chunk.
__global__ __launch_bounds__(512, 2) void gemm2p(
    const UST* __restrict__ Agh, const UST* __restrict__ Agl,
    const UST* __restrict__ Bgh, const UST* __restrict__ Bgl,
    const float* __restrict__ bias, float* __restrict__ Cf,
    UST* __restrict__ Cb,
    int M, int N, int K, int pmode, int bn0)
{
  // [buf][Ah,Al,Bh,Bl][256*32] = 128 KiB
  __shared__ __align__(16) UST lds[2][4][8192];

  const int tid  = threadIdx.x;
  const int lane = tid & 63;
  const int wv   = tid >> 6;          // 0..7
  const int wr   = wv >> 2;           // 0..1 (M half)
  const int wcn  = wv & 3;            // 0..3 (N quarter)
  const int lm   = lane & 15;
  const int lq   = lane >> 4;

  // T1: bijective XCD swizzle (m204)
  const int gx  = gridDim.x;
  const int nwg = gx * gridDim.y;
  int wgid;
  {
    const int orig = blockIdx.y * gx + blockIdx.x;
    const int q = nwg >> 3, r = nwg & 7;
    const int xcd = orig & 7, off = orig >> 3;
    wgid = (xcd < r ? xcd * (q + 1) : r * (q + 1) + (xcd - r) * q) + off;
  }
  const int m0 = (wgid / gx) * 256;
  const int n0 = (wgid % gx) * 256;

  // ---- staging: wave wv covers rows wv*16..+15 of each 128-row half.
  // lane l: LDS row wv*16 + (l>>2), chunk l&3 (linear dest). Source chunk is
  // the inverse swizzle: csrc = (l&3) ^ ((row>>3)&1)<<1, row bit3 = (l>>5)&1.
  const int l2   = lane >> 2;                         // row within wave region
  const int csrc = (lane & 3) ^ (((lane >> 5) & 1) << 1);
  const int sA0 = m0 + wv * 16 + l2;
  const int sB0 = n0 + wv * 16 + l2;
  const size_t rA0 = (pmode == 1) ? tok_row(sA0, bn0)       : (size_t)sA0;
  const size_t rA1 = (pmode == 1) ? tok_row(sA0 + 128, bn0) : (size_t)(sA0 + 128);
  const UST* pA0h = Agh + rA0 * K + csrc * 8;
  const UST* pA0l = Agl + rA0 * K + csrc * 8;
  const UST* pA1h = Agh + rA1 * K + csrc * 8;
  const UST* pA1l = Agl + rA1 * K + csrc * 8;
  const UST* pB0h = Bgh + (size_t)sB0 * K + csrc * 8;
  const UST* pB0l = Bgl + (size_t)sB0 * K + csrc * 8;
  const UST* pB1h = Bgh + (size_t)(sB0 + 128) * K + csrc * 8;
  const UST* pB1l = Bgl + (size_t)(sB0 + 128) * K + csrc * 8;
  const int ldst = wv * 512;          // UST offset of wave region within a half

  // ---- read side: swizzled chunk ck = lq ^ ((row>>3)&1)<<1, row bit3 = lm bit3
  const int ck = lq ^ (((lm >> 3) & 1) << 1);
  const int raBase = (wr * 128 + lm) * 32 + ck * 8;   // + i*512, i=0..7
  const int rbBase = (wcn * 64 + lm) * 32 + ck * 8;   // + j*512, j=0..3

  f32x4 acc[8][4] = {};

#define STAGE(bufW, koff) do { \
  gl_lds16(pA0h + (koff), (bufW)[0] + 0 * 4096 + ldst); \
  gl_lds16(pA1h + (koff), (bufW)[0] + 1 * 4096 + ldst); \
  gl_lds16(pA0l + (koff), (bufW)[1] + 0 * 4096 + ldst); \
  gl_lds16(pA1l + (koff), (bufW)[1] + 1 * 4096 + ldst); \
  gl_lds16(pB0h + (koff), (bufW)[2] + 0 * 4096 + ldst); \
  gl_lds16(pB1h + (koff), (bufW)[2] + 1 * 4096 + ldst); \
  gl_lds16(pB0l + (koff), (bufW)[3] + 0 * 4096 + ldst); \
  gl_lds16(pB1l + (koff), (bufW)[3] + 1 * 4096 + ldst); \
} while (0)

  // prologue: stage tile 0 into buf 0
  STAGE(lds[0], 0);

  const int NT = K >> 5;  // 768/32 = 24
  for (int u = 0; u < NT; ++u) {
    UST (*bufR)[8192] = lds[u & 1];
    UST (*bufW)[8192] = lds[(u & 1) ^ 1];
    WAIT_VM0();           // my staged loads for bufR have landed
    SBAR();               // everyone's landed; everyone done reading bufW
    SCHED0();
    if (u + 1 < NT) STAGE(bufW, (u + 1) * 32);

    // B fragments for the whole tile (8 x ds_read_b128)
    bf16x8 bfh[4], bfl[4];
#pragma unroll
    for (int j = 0; j < 4; ++j) {
      const int off = rbBase + j * 512;
      bfh[j] = *(const bf16x8*)(bufR[2] + off);
      bfl[j] = *(const bf16x8*)(bufR[3] + off);
    }
    // two M-halves: 8 A-frag reads + 48 MFMA each
#pragma unroll
    for (int mh = 0; mh < 2; ++mh) {
      bf16x8 afh[4], afl[4];
#pragma unroll
      for (int ii = 0; ii < 4; ++ii) {
        const int off = raBase + (mh * 4 + ii) * 512;
        afh[ii] = *(const bf16x8*)(bufR[0] + off);
        afl[ii] = *(const bf16x8*)(bufR[1] + off);
      }
      __builtin_amdgcn_s_setprio(1);
#pragma unroll
      for (int ii = 0; ii < 4; ++ii)
#pragma unroll
        for (int jj = 0; jj < 4; ++jj) {
          f32x4 c = acc[mh * 4 + ii][jj];
          c = __builtin_amdgcn_mfma_f32_16x16x32_bf16(afh[ii], bfh[jj], c, 0, 0, 0);
          c = __builtin_amdgcn_mfma_f32_16x16x32_bf16(afh[ii], bfl[jj], c, 0, 0, 0);
          c = __builtin_amdgcn_mfma_f32_16x16x32_bf16(afl[ii], bfh[jj], c, 0, 0, 0);
          acc[mh * 4 + ii][jj] = c;
        }
      __builtin_amdgcn_s_setprio(0);
    }
  }
#undef STAGE

  // epilogue: C/D layout col=lane&15, row=quad*4+reg
#pragma unroll
  for (int j = 0; j < 4; ++j) {
    const int n = n0 + wcn * 64 + j * 16 + lm;
    const float bv = bias ? bias[n] : 0.0f;
#pragma unroll
    for (int i = 0; i < 8; ++i) {
      const int pbase = m0 + wr * 128 + i * 16 + lq * 4;
#pragma unroll
      for (int r = 0; r < 4; ++r) {
        const int p = pbase + r;
        const size_t g = (pmode == 2) ? tok_row(p, bn0) : (size_t)p;
        const float v = acc[i][j][r] + bv;
        if (Cb) Cb[g * (size_t)N + n] = f2bf(v);
        else    Cf[g * (size_t)N + n] = v;
      }
    }
  }
}

// One block per (chunk-local bn, head): causal attention, T=64, hd=64.
// qkv: chunk-local (64*NBc, 2304) bf16.  out: split bf16 hi/lo (64*NBc, 768).
#define SQ_STRIDE 67
#define TS 72

__global__ __launch_bounds__(256) void attn64(
    const UST* __restrict__ qkv, UST* __restrict__ oh, UST* __restrict__ ol)
{
  const int nl = blockIdx.x;
  const int h  = blockIdx.y;

  __shared__ __align__(16) UST Qs[64 * TS];
  __shared__ __align__(16) UST Ks[64 * TS];
  __shared__ __align__(16) UST Vt[64 * TS];   // V^T, XOR-swizzled k-blocks
  __shared__ __align__(16) UST Ps[64 * TS];   // exp(S-M) bf16
  __shared__ float Ss[64 * SQ_STRIDE];
  __shared__ float red[4 * 64];
  __shared__ float denom[64];

  const int tid  = threadIdx.x;
  const int lane = tid & 63;
  const int wv   = tid >> 6;
  const int lm   = lane & 15;
  const int lq   = lane >> 4;

  // ---- stage Q, K (bf16) and V^T (XOR-swizzled) ----
#pragma unroll
  for (int it = 0; it < 2; ++it) {
    const int idx = it * 256 + tid;      // ushort8-chunk id, 0..511
    const int t   = idx >> 3;            // row 0..63
    const int f0  = (idx & 7) * 8;       // col 0..56
    const UST* row = qkv + (size_t)(nl * 64 + t) * 2304 + h * 64 + f0;
    uint4 qv = *(const uint4*)row;
    uint4 kv = *(const uint4*)(row + 768);
    uint4 vv = *(const uint4*)(row + 1536);
    *(uint4*)(&Qs[t * TS + f0]) = qv;
    *(uint4*)(&Ks[t * TS + f0]) = kv;
    UST vs[8];
    *(uint4*)vs = vv;
    const int cb = t >> 3;
#pragma unroll
    for (int i = 0; i < 8; ++i) {
      const int d = f0 + i;
      // element V[t][d] stored at Vt[d][ ((cb ^ (d>>3))&7)*8 + (t&7) ]
      Vt[d * TS + (((cb ^ (d >> 3)) & 7) << 3) + (t & 7)] = vs[i];
    }
  }
  __syncthreads();

  // ---- S = Q K^T : wave wv computes rows [wv*16, wv*16+16) x all 64 cols ----
  f32x4 accS[4] = {};
#pragma unroll
  for (int s = 0; s < 2; ++s) {
    bf16x8 aq = *(const bf16x8*)(&Qs[(wv * 16 + lm) * TS + s * 32 + lq * 8]);
#pragma unroll
    for (int j = 0; j < 4; ++j) {
      bf16x8 bk = *(const bf16x8*)(&Ks[(j * 16 + lm) * TS + s * 32 + lq * 8]);
      accS[j] = __builtin_amdgcn_mfma_f32_16x16x32_bf16(aq, bk, accS[j], 0, 0, 0);
    }
  }

  // write masked, scaled scores (C/D layout: col=lane&15, row=quad*4+reg)
#pragma unroll
  for (int j = 0; j < 4; ++j)
#pragma unroll
    for (int r = 0; r < 4; ++r) {
      const int q = wv * 16 + lq * 4 + r;
      const int c = j * 16 + lm;
      Ss[q * SQ_STRIDE + c] = (c > q) ? -1e30f : accS[j][r] * 0.125f;
    }
  __syncthreads();

  // ---- softmax: thread handles row r=tid>>2, cols [seg*16, seg*16+16) ----
  {
    const int r = tid >> 2;
    const int seg = tid & 3;
    const float* srow = &Ss[r * SQ_STRIDE + seg * 16];
    float mx = -1e30f;
#pragma unroll
    for (int c = 0; c < 16; ++c) mx = fmaxf(mx, srow[c]);
    red[seg * 64 + r] = mx;
  }
  __syncthreads();
  {
    const int r = tid >> 2;
    const int seg = tid & 3;
    const float M = fmaxf(fmaxf(red[r], red[64 + r]), fmaxf(red[128 + r], red[192 + r]));
    float ssum = 0.f;
#pragma unroll
    for (int c = 0; c < 16; ++c) {
      const int col = seg * 16 + c;
      float e = 0.f;
      if (col <= r) e = __expf(Ss[r * SQ_STRIDE + col] - M);
      Ps[r * TS + col] = f2bf(e);
      ssum += e;
    }
    __syncthreads();           // all reads of red done before overwrite
    red[seg * 64 + r] = ssum;
  }
  __syncthreads();
  if (tid < 64)
    denom[tid] = red[tid] + red[64 + tid] + red[128 + tid] + red[192 + tid];
  __syncthreads();

  // ---- O = P V : wave wv computes rows [wv*16,+16) x d=0..63 ----
  f32x4 accO[4] = {};
#pragma unroll
  for (int s = 0; s < 2; ++s) {
    bf16x8 ap = *(const bf16x8*)(&Ps[(wv * 16 + lm) * TS + s * 32 + lq * 8]);
#pragma unroll
    for (int j = 0; j < 4; ++j) {
      const int d = j * 16 + lm;
      const int cb = s * 4 + lq;
      bf16x8 bv = *(const bf16x8*)(&Vt[d * TS + (((cb ^ (d >> 3)) & 7) << 3)]);
      accO[j] = __builtin_amdgcn_mfma_f32_16x16x32_bf16(ap, bv, accO[j], 0, 0, 0);
    }
  }

  float inv[4];
#pragma unroll
  for (int r = 0; r < 4; ++r) inv[r] = 1.0f / denom[wv * 16 + lq * 4 + r];
#pragma unroll
  for (int j = 0; j < 4; ++j)
#pragma unroll
    for (int r = 0; r < 4; ++r) {
      const int q = wv * 16 + lq * 4 + r;
      const int d = j * 16 + lm;
      const float o = accO[j][r] * inv[r];
      const __bf16 hb = (__bf16)o;
      const size_t gi = (size_t)(nl * 64 + q) * 768 + h * 64 + d;
      oh[gi] = __builtin_bit_cast(UST, hb);
      ol[gi] = f2bf(o - (float)hb);
    }
}

// Diagnostic fallback: ws too small -> fill output with 1.0f.
__global__ void fill_one(float* p, int n) {
  for (int i = blockIdx.x * 256 + threadIdx.x; i < n; i += gridDim.x * 256)
    p[i] = 1.0f;
}

extern "C" void kernel_launch(void* const* d_in, const int* in_sizes, int n_in,
                              void* d_out, int out_size, void* d_ws, size_t ws_size,
                              hipStream_t stream)
{
  const float* x      = (const float*)d_in[0];
  const float* w_qkv  = (const float*)d_in[1];
  const float* w_proj = (const float*)d_in[2];
  const float* b_proj = (const float*)d_in[3];
  float* out = (float*)d_out;

  const size_t XN = 38535168ull;          // 4*64*196*768
  const size_t WQ = 2304ull * 768;        // 1769472
  const size_t WP = 768ull * 768;         // 589824
  const size_t fixed_b = 2 * (2 * XN + 2 * WQ + 2 * WP);  // bytes: Xh/Xl,Wh/Wl,Ph/Pl
  // per-bn bytes: qkv 64*2304*2 + Oh/Ol 2*64*768*2
  const size_t per_bn = 64ull * 2304 * 2 + 2ull * 64 * 768 * 2;   // 491520

  // M = NBc*64 must be a multiple of 256 -> NBc % 4 == 0
  static const int cands[] = {784, 392, 196, 112, 56, 28, 8, 4};
  int NBc = 0;
  for (int i = 0; i < 8; ++i) {
    if (fixed_b + (size_t)cands[i] * per_bn <= ws_size) { NBc = cands[i]; break; }
  }

  if (NBc == 0) {
    fill_one<<<512, 256, 0, stream>>>(out, out_size);
    return;
  }

  UST* Xh  = (UST*)d_ws;
  UST* Xl  = Xh + XN;
  UST* Wh  = Xl + XN;
  UST* Wl  = Wh + WQ;
  UST* Ph  = Wl + WQ;
  UST* Pl  = Ph + WP;
  UST* qkv = Pl + WP;                       // NBc*64*2304 bf16
  UST* Oh  = qkv + (size_t)NBc * 64 * 2304;
  UST* Ol  = Oh + (size_t)NBc * 64 * 768;

  // one-time splits (per launch)
  split_f32<<<2048, 256, 0, stream>>>(x, Xh, Xl, (int)(XN / 8));
  split_f32<<<864, 256, 0, stream>>>(w_qkv, Wh, Wl, (int)(WQ / 8));
  split_f32<<<288, 256, 0, stream>>>(w_proj, Ph, Pl, (int)(WP / 8));

  const int Mi = NBc * 64;
  for (int bn0 = 0; bn0 < 784; bn0 += NBc) {
    dim3 g1(2304 / 256, Mi / 256);
    gemm2p<<<g1, 512, 0, stream>>>(Xh, Xl, Wh, Wl, nullptr, nullptr, qkv,
                                   Mi, 2304, 768, /*pmode=*/1, bn0);
    dim3 ga(NBc, 12);
    attn64<<<ga, 256, 0, stream>>>(qkv, Oh, Ol);
    dim3 g2(768 / 256, Mi / 256);
    gemm2p<<<g2, 512, 0, stream>>>(Oh, Ol, Ph, Pl, b_proj, out, nullptr,
                                   Mi, 768, 768, /*pmode=*/2, bn0);
  }
}